// Round 1
// baseline (387.201 us; speedup 1.0000x reference)
//
#include <hip/hip_runtime.h>
#include <hip/hip_fp16.h>
#include <math.h>

#define N_NODES 100000
#define N_EDGES 1600000
#define IN_DIM 256
#define OUT_DIM 64

#define SCAN_CHUNK 2048
#define NBLK ((N_NODES + 1 + SCAN_CHUNK - 1) / SCAN_CHUNK)  // 49

#define NPART 8
#define PART_SIZE ((N_NODES + NPART - 1) / NPART)  // 12500 rows per partition

// Bucketed edge staging
#define BCAP 208896              // per-bucket capacity (mean 200000, ~20 sd slack)
#define CHUNK_E 4096             // edges per bin block
#define NBIN_BLK ((N_EDGES + CHUNK_E - 1) / CHUNK_E)  // 391
#define LCAP 688                 // per-bucket LDS capacity (mean 512, sd ~21)

// ---- workspace layout (bytes) ----
// X region [0, 25.6MB): time-shared — int2 bp[8][BCAP] (13.37MB) during CSR build,
// then x[N_NODES][64] fp16 (12.8MB) written by gemm AFTER permute consumed bp.
#define X_OFF         0UL
#define COUNTS_OFF    25600000UL   // 400,000 B: int counts[N_NODES]
#define OFFSETS_OFF   26000000UL   // 400,004 B: int offsets[N_NODES+1]
#define CURSOR_OFF    26400016UL   // 400,000 B: int cursor[N_NODES]; first 64KB doubles as W-image (convert_weight runs after permute)
#define BLOCKSUMS_OFF 26800016UL   // 256 B
#define BLOCKOFFS_OFF 26800272UL   // 256 B
#define BCUR_OFF      26800576UL   // 512 B: 8 bucket cursors padded to 64B lines
#define SORTED_OFF    26801088UL   // 6,400,000 B: int sorted_cols[N_EDGES]
// total ~33.2 MB (same footprint as the proven previous layout)

typedef short bf16x8 __attribute__((ext_vector_type(8)));
typedef float f32x4 __attribute__((ext_vector_type(4)));

// ---------------- Weight -> bf16 hi/lo B-fragment image (64 KB) ----------------
__global__ __launch_bounds__(256) void convert_weight(const float* __restrict__ w,
                                                      ushort* __restrict__ img) {
    const int g = blockIdx.x * 256 + threadIdx.x;  // 0..16383
    const int j = g & 7, l = (g >> 3) & 63, ts = g >> 9;  // ts = t*8+s
    const int s = ts & 7, t = ts >> 3;
    const int k = s * 32 + (l >> 4) * 8 + j;
    const int c = t * 16 + (l & 15);
    const float v = w[k * OUT_DIM + c];
    const unsigned b = __float_as_uint(v);
    const float r = v - __uint_as_float(b & 0xFFFF0000u);  // residual after hi-truncation
    img[(ts * 2 + 0) * 512 + l * 8 + j] = (ushort)(b >> 16);
    img[(ts * 2 + 1) * 512 + l * 8 + j] = (ushort)(__float_as_uint(r) >> 16);
}

// ---------------- GEMM via MFMA, fp32 accuracy by bf16 hi/lo 3-term split ----------------
__global__ __launch_bounds__(256) void gemm_mfma(const float* __restrict__ inputs,
                                                 const ushort* __restrict__ wimg,
                                                 __half* __restrict__ x) {
    __shared__ ushort lds[32768];  // 64 KB -> 2 blocks/CU
    const int tid = threadIdx.x;

    #pragma unroll
    for (int i = 0; i < 16; ++i) {
        const int c = tid + i * 256;  // 16B-chunk index 0..4095
        *(int4*)(lds + c * 8) = *(const int4*)(wimg + c * 8);
    }
    __syncthreads();

    const int wv = tid >> 6, l = tid & 63;
    const int rbase = blockIdx.x * 64 + wv * 16;
    const int arow_idx = rbase + (l & 15);
    const int row_c = arow_idx < N_NODES ? arow_idx : N_NODES - 1;  // clamp loads; stores guarded
    const float* arow = inputs + (size_t)row_c * IN_DIM;
    const int koff = (l >> 4) * 8;

    bf16x8 ah[8], al[8];
    #pragma unroll
    for (int s = 0; s < 8; ++s) {
        const float4 p = *(const float4*)(arow + s * 32 + koff);
        const float4 q = *(const float4*)(arow + s * 32 + koff + 4);
        const float v[8] = {p.x, p.y, p.z, p.w, q.x, q.y, q.z, q.w};
        #pragma unroll
        for (int j = 0; j < 8; ++j) {
            const unsigned b = __float_as_uint(v[j]);
            const float r = v[j] - __uint_as_float(b & 0xFFFF0000u);
            ah[s][j] = (short)(b >> 16);
            al[s][j] = (short)(__float_as_uint(r) >> 16);
        }
    }

    f32x4 acc[4];
    #pragma unroll
    for (int t = 0; t < 4; ++t) acc[t] = (f32x4){0.f, 0.f, 0.f, 0.f};

    const bf16x8* b8 = (const bf16x8*)lds;
    #pragma unroll
    for (int t = 0; t < 4; ++t) {
        #pragma unroll
        for (int s = 0; s < 8; ++s) {
            const bf16x8 bh = b8[((t * 8 + s) * 2 + 0) * 64 + l];
            const bf16x8 blo = b8[((t * 8 + s) * 2 + 1) * 64 + l];
            acc[t] = __builtin_amdgcn_mfma_f32_16x16x32_bf16(ah[s], bh, acc[t], 0, 0, 0);
            acc[t] = __builtin_amdgcn_mfma_f32_16x16x32_bf16(al[s], bh, acc[t], 0, 0, 0);
            acc[t] = __builtin_amdgcn_mfma_f32_16x16x32_bf16(ah[s], blo, acc[t], 0, 0, 0);
        }
    }

    const int mbase = rbase + (l >> 4) * 4;
    #pragma unroll
    for (int reg = 0; reg < 4; ++reg) {
        const int row = mbase + reg;
        if (row < N_NODES) {
            #pragma unroll
            for (int t = 0; t < 4; ++t)
                x[(size_t)row * OUT_DIM + t * 16 + (l & 15)] = __float2half(acc[t][reg]);
        }
    }
}

// ---------------- CSR step 1: bin edges into 8 row-partition buckets ----------------
// LDS-staged: per-block LDS buckets filled via LDS atomics, one global atomic per
// (block,bucket) to reserve space, fully-coalesced int2 flush. Per-row histogram
// fused in as no-return global atomics (replaces hist_kernel).
__global__ __launch_bounds__(256) void bin_kernel(const int* __restrict__ rows,
                                                  const int* __restrict__ cols,
                                                  int* __restrict__ counts,
                                                  int* __restrict__ bcur,
                                                  int2* __restrict__ bp) {
    __shared__ int2 lbuf[NPART][LCAP];   // 44,032 B
    __shared__ int lcnt[NPART];
    __shared__ int lbase[NPART];
    const int tid = threadIdx.x;
    if (tid < NPART) lcnt[tid] = 0;
    __syncthreads();

    const int base = blockIdx.x * CHUNK_E;
    #pragma unroll
    for (int g = 0; g < 4; ++g) {
        const int e = base + (g * 256 + tid) * 4;
        if (e < N_EDGES) {  // N_EDGES % 4 == 0, so whole int4 in range
            const int4 r4 = *(const int4*)(rows + e);
            const int4 c4 = *(const int4*)(cols + e);
            const int rr[4] = {r4.x, r4.y, r4.z, r4.w};
            const int cc[4] = {c4.x, c4.y, c4.z, c4.w};
            #pragma unroll
            for (int u = 0; u < 4; ++u) {
                atomicAdd(&counts[rr[u]], 1);         // fused histogram (no return)
                const int b = rr[u] / PART_SIZE;      // const divide -> magic mul
                const int p = atomicAdd(&lcnt[b], 1);
                if (p < LCAP) {
                    lbuf[b][p] = make_int2(rr[u], cc[u]);
                } else {  // statistically-never spill path (keeps correctness unconditional)
                    const int gp = atomicAdd(&bcur[b * 16], 1);
                    bp[(size_t)b * BCAP + gp] = make_int2(rr[u], cc[u]);
                }
            }
        }
    }
    __syncthreads();
    if (tid < NPART) {
        const int tot = min(lcnt[tid], LCAP);
        lbase[tid] = atomicAdd(&bcur[tid * 16], tot);
    }
    __syncthreads();
    #pragma unroll
    for (int b = 0; b < NPART; ++b) {
        const int tot = min(lcnt[b], LCAP);
        const int gb = lbase[b];
        for (int i = tid; i < tot; i += 256)
            bp[(size_t)b * BCAP + gb + i] = lbuf[b][i];  // coalesced 8B stores
    }
}

// ---------------- CSR step 2a: per-chunk totals ----------------
__global__ __launch_bounds__(256) void scan_reduce(const int* __restrict__ counts,
                                                   int* __restrict__ blocksums) {
    __shared__ int lds[256];
    const int b = blockIdx.x, t = threadIdx.x;
    const int base = b * SCAN_CHUNK + t * 8;
    int s = 0;
    #pragma unroll
    for (int i = 0; i < 8; ++i) {
        const int idx = base + i;
        s += (idx < N_NODES) ? counts[idx] : 0;
    }
    lds[t] = s; __syncthreads();
    for (int off = 128; off > 0; off >>= 1) {
        if (t < off) lds[t] += lds[t + off];
        __syncthreads();
    }
    if (t == 0) blocksums[b] = lds[0];
}

// ---------------- CSR step 2b: exclusive scan of chunk totals (1 wave) ----------------
__global__ __launch_bounds__(64) void scan_toplevel(const int* __restrict__ blocksums,
                                                    int* __restrict__ blockoffs) {
    const int t = threadIdx.x;
    const int mine = (t < NBLK) ? blocksums[t] : 0;
    int v = mine;
    #pragma unroll
    for (int d = 1; d < 64; d <<= 1) {
        const int u = __shfl_up(v, d, 64);
        if (t >= d) v += u;
    }
    if (t < NBLK) blockoffs[t] = v - mine;  // exclusive
}

// ---------------- CSR step 2c: full exclusive scan -> offsets, cursor ----------------
__global__ __launch_bounds__(256) void scan_final(const int* __restrict__ counts,
                                                  const int* __restrict__ blockoffs,
                                                  int* __restrict__ offsets,
                                                  int* __restrict__ cursor) {
    __shared__ int a[256], bbuf[256];
    const int b = blockIdx.x, t = threadIdx.x;
    const int base = b * SCAN_CHUNK + t * 8;
    int v[8]; int s = 0;
    #pragma unroll
    for (int i = 0; i < 8; ++i) {
        const int idx = base + i;
        v[i] = (idx < N_NODES) ? counts[idx] : 0;
        s += v[i];
    }
    a[t] = s; __syncthreads();
    int* src = a; int* dst = bbuf;
    for (int off = 1; off < 256; off <<= 1) {
        const int x = src[t] + ((t >= off) ? src[t - off] : 0);
        dst[t] = x; __syncthreads();
        int* tmp = src; src = dst; dst = tmp;
    }
    int run = blockoffs[b] + (src[t] - s);
    #pragma unroll
    for (int i = 0; i < 8; ++i) {
        const int idx = base + i;
        if (idx <= N_NODES) {
            offsets[idx] = run;
            if (idx < N_NODES) cursor[idx] = run;
        }
        run += v[i];
    }
}

// ---------------- CSR step 3: bucket-local, XCD-pinned permute ----------------
// Bucket b's working set (pair stream ~1.7MB + cursor slice 50KB + write window
// 800KB) fits one XCD's 4MB L2; blockIdx&7 pins it there (round-robin heuristic).
__global__ __launch_bounds__(256) void permute_kernel(const int2* __restrict__ bp,
                                                      const int* __restrict__ bcur,
                                                      int* __restrict__ cursor,
                                                      int* __restrict__ sorted_cols) {
    const int b = blockIdx.x & (NPART - 1);
    const int n = bcur[b * 16];
    const int stride = (gridDim.x >> 3) * 256;
    for (int i = (blockIdx.x >> 3) * 256 + threadIdx.x; i < n; i += stride) {
        const int2 e = bp[(size_t)b * BCAP + i];
        const int pos = atomicAdd(&cursor[e.x], 1);
        sorted_cols[pos] = e.y;
    }
}

// ---------------- Pull-mode aggregate (fp16 gather) + fused sigmoid ----------------
__global__ __launch_bounds__(256) void aggregate_kernel(const int* __restrict__ offsets,
                                                        const int* __restrict__ sorted_cols,
                                                        const __half* __restrict__ x,
                                                        float* __restrict__ out) {
    const int row = blockIdx.x * 4 + (threadIdx.x >> 6);
    const int lane = threadIdx.x & 63;
    if (row >= N_NODES) return;
    const int start = offsets[row];
    const int end = offsets[row + 1];
    float acc = 0.f;
    int j = start;
    for (; j + 7 < end; j += 8) {
        int c[8];
        #pragma unroll
        for (int u = 0; u < 8; ++u) c[u] = sorted_cols[j + u];
        float a[8];
        #pragma unroll
        for (int u = 0; u < 8; ++u) a[u] = __half2float(x[(size_t)c[u] * OUT_DIM + lane]);
        acc += ((a[0] + a[1]) + (a[2] + a[3])) + ((a[4] + a[5]) + (a[6] + a[7]));
    }
    for (; j < end; ++j)
        acc += __half2float(x[(size_t)sorted_cols[j] * OUT_DIM + lane]);
    out[(size_t)row * OUT_DIM + lane] = 1.f / (1.f + __expf(-acc));
}

extern "C" void kernel_launch(void* const* d_in, const int* in_sizes, int n_in,
                              void* d_out, int out_size, void* d_ws, size_t ws_size,
                              hipStream_t stream) {
    const float* inputs = (const float*)d_in[0];
    const int* edge_index = (const int*)d_in[1];  // [2, N_EDGES], int32 on device
    const float* weight = (const float*)d_in[2];
    float* out = (float*)d_out;

    char* ws = (char*)d_ws;
    __half* x        = (__half*)(ws + X_OFF);
    int2* bp         = (int2*)(ws + X_OFF);       // time-aliases x: dead before gemm writes
    int* counts      = (int*)(ws + COUNTS_OFF);
    int* offsets     = (int*)(ws + OFFSETS_OFF);
    int* cursor      = (int*)(ws + CURSOR_OFF);
    ushort* wimg     = (ushort*)(ws + CURSOR_OFF);  // 64KB alias; cursor dead after permute
    int* blocksums   = (int*)(ws + BLOCKSUMS_OFF);
    int* blockoffs   = (int*)(ws + BLOCKOFFS_OFF);
    int* bcur        = (int*)(ws + BCUR_OFF);
    int* sorted_cols = (int*)(ws + SORTED_OFF);

    const int* rows = edge_index;
    const int* cols = edge_index + N_EDGES;

    hipMemsetAsync(counts, 0, N_NODES * sizeof(int), stream);
    hipMemsetAsync(bcur, 0, NPART * 16 * sizeof(int), stream);

    // ---- CSR build (bucketed counting sort) ----
    bin_kernel<<<NBIN_BLK, 256, 0, stream>>>(rows, cols, counts, bcur, bp);
    scan_reduce<<<NBLK, 256, 0, stream>>>(counts, blocksums);
    scan_toplevel<<<1, 64, 0, stream>>>(blocksums, blockoffs);
    scan_final<<<NBLK, 256, 0, stream>>>(counts, blockoffs, offsets, cursor);
    permute_kernel<<<8 * 192, 256, 0, stream>>>(bp, bcur, cursor, sorted_cols);

    // ---- dense projection (x overwrites bp region; wimg overwrites dead cursor) ----
    convert_weight<<<64, 256, 0, stream>>>(weight, wimg);
    gemm_mfma<<<(N_NODES + 63) / 64, 256, 0, stream>>>(inputs, wimg, x);

    // ---- gather-aggregate + sigmoid ----
    aggregate_kernel<<<(N_NODES + 3) / 4, 256, 0, stream>>>(offsets, sorted_cols, x, out);
}

// Round 2
// 274.992 us; speedup vs baseline: 1.4080x; 1.4080x over previous
//
#include <hip/hip_runtime.h>
#include <hip/hip_fp16.h>
#include <math.h>

#define N_NODES 100000
#define N_EDGES 1600000
#define IN_DIM 256
#define OUT_DIM 64

// ---- two-level LDS counting sort ----
#define NB 256                   // buckets
#define RPB 391                  // rows per bucket; 256*391 = 100096 >= N_NODES
#define BCAP 6912                // per-bucket global capacity (mean 6250, +8.3 sd)
#define CAP 32                   // per-bucket LDS staging slots (mean 8, Poisson tail ~1e-12/cell)
#define CHUNK_E 2048             // edges per bin block
#define NBIN_BLK ((N_EDGES + CHUNK_E - 1) / CHUNK_E)  // 782

// ---- workspace layout (bytes) ----
// [0, 25.6MB): time-shared — packed buckets bp[NB][BCAP] (7.08MB) during CSR build,
// then x[N_NODES][64] fp16 (12.8MB) written by gemm AFTER sort_kernel consumed bp.
#define X_OFF         0UL
#define WIMG_OFF      25600000UL   // 64KB weight image
#define OFFSETS_OFF   26000000UL   // 400,004 B: int offsets[N_NODES+1]
#define BCUR_OFF      26400016UL   // 1KB: int bcur[NB]
#define SORTED_OFF    26801088UL   // 6,400,000 B: int sorted_cols[N_EDGES]
// total ~33.2 MB (same footprint as proven layout)

typedef short bf16x8 __attribute__((ext_vector_type(8)));
typedef float f32x4 __attribute__((ext_vector_type(4)));

// ---------------- Weight -> bf16 hi/lo B-fragment image (64 KB) ----------------
__global__ __launch_bounds__(256) void convert_weight(const float* __restrict__ w,
                                                      ushort* __restrict__ img) {
    const int g = blockIdx.x * 256 + threadIdx.x;  // 0..16383
    const int j = g & 7, l = (g >> 3) & 63, ts = g >> 9;  // ts = t*8+s
    const int s = ts & 7, t = ts >> 3;
    const int k = s * 32 + (l >> 4) * 8 + j;
    const int c = t * 16 + (l & 15);
    const float v = w[k * OUT_DIM + c];
    const unsigned b = __float_as_uint(v);
    const float r = v - __uint_as_float(b & 0xFFFF0000u);  // residual after hi-truncation
    img[(ts * 2 + 0) * 512 + l * 8 + j] = (ushort)(b >> 16);
    img[(ts * 2 + 1) * 512 + l * 8 + j] = (ushort)(__float_as_uint(r) >> 16);
}

// ---------------- GEMM via MFMA, fp32 accuracy by bf16 hi/lo 3-term split ----------------
__global__ __launch_bounds__(256) void gemm_mfma(const float* __restrict__ inputs,
                                                 const ushort* __restrict__ wimg,
                                                 __half* __restrict__ x) {
    __shared__ ushort lds[32768];  // 64 KB -> 2 blocks/CU
    const int tid = threadIdx.x;

    #pragma unroll
    for (int i = 0; i < 16; ++i) {
        const int c = tid + i * 256;  // 16B-chunk index 0..4095
        *(int4*)(lds + c * 8) = *(const int4*)(wimg + c * 8);
    }
    __syncthreads();

    const int wv = tid >> 6, l = tid & 63;
    const int rbase = blockIdx.x * 64 + wv * 16;
    const int arow_idx = rbase + (l & 15);
    const int row_c = arow_idx < N_NODES ? arow_idx : N_NODES - 1;  // clamp loads; stores guarded
    const float* arow = inputs + (size_t)row_c * IN_DIM;
    const int koff = (l >> 4) * 8;

    bf16x8 ah[8], al[8];
    #pragma unroll
    for (int s = 0; s < 8; ++s) {
        const float4 p = *(const float4*)(arow + s * 32 + koff);
        const float4 q = *(const float4*)(arow + s * 32 + koff + 4);
        const float v[8] = {p.x, p.y, p.z, p.w, q.x, q.y, q.z, q.w};
        #pragma unroll
        for (int j = 0; j < 8; ++j) {
            const unsigned b = __float_as_uint(v[j]);
            const float r = v[j] - __uint_as_float(b & 0xFFFF0000u);
            ah[s][j] = (short)(b >> 16);
            al[s][j] = (short)(__float_as_uint(r) >> 16);
        }
    }

    f32x4 acc[4];
    #pragma unroll
    for (int t = 0; t < 4; ++t) acc[t] = (f32x4){0.f, 0.f, 0.f, 0.f};

    const bf16x8* b8 = (const bf16x8*)lds;
    #pragma unroll
    for (int t = 0; t < 4; ++t) {
        #pragma unroll
        for (int s = 0; s < 8; ++s) {
            const bf16x8 bh = b8[((t * 8 + s) * 2 + 0) * 64 + l];
            const bf16x8 blo = b8[((t * 8 + s) * 2 + 1) * 64 + l];
            acc[t] = __builtin_amdgcn_mfma_f32_16x16x32_bf16(ah[s], bh, acc[t], 0, 0, 0);
            acc[t] = __builtin_amdgcn_mfma_f32_16x16x32_bf16(al[s], bh, acc[t], 0, 0, 0);
            acc[t] = __builtin_amdgcn_mfma_f32_16x16x32_bf16(ah[s], blo, acc[t], 0, 0, 0);
        }
    }

    const int mbase = rbase + (l >> 4) * 4;
    #pragma unroll
    for (int reg = 0; reg < 4; ++reg) {
        const int row = mbase + reg;
        if (row < N_NODES) {
            #pragma unroll
            for (int t = 0; t < 4; ++t)
                x[(size_t)row * OUT_DIM + t * 16 + (l & 15)] = __float2half(acc[t][reg]);
        }
    }
}

// ---------------- CSR step 1: bin edges into 256 row-buckets (packed 4B) ----------------
// pack = (rloc << 17) | col, rloc = r - bucket*RPB (<391 -> 9 bits), col < 2^17.
// Only global atomics: one reservation per (block,bucket) = 200K total (vs 1.6M before).
__global__ __launch_bounds__(256) void bin_kernel(const int* __restrict__ rows,
                                                  const int* __restrict__ cols,
                                                  int* __restrict__ bcur,
                                                  int* __restrict__ bp) {
    __shared__ int lbuf[NB * CAP];   // 32 KB
    __shared__ int lcnt[NB], ltot[NB], lbase[NB];
    const int tid = threadIdx.x;
    lcnt[tid] = 0;
    __syncthreads();

    const int base = blockIdx.x * CHUNK_E;
    #pragma unroll
    for (int g = 0; g < 2; ++g) {
        const int e = base + (g * 256 + tid) * 4;
        if (e < N_EDGES) {  // N_EDGES % 4 == 0, whole int4 in range
            const int4 r4 = *(const int4*)(rows + e);
            const int4 c4 = *(const int4*)(cols + e);
            const int rr[4] = {r4.x, r4.y, r4.z, r4.w};
            const int cc[4] = {c4.x, c4.y, c4.z, c4.w};
            #pragma unroll
            for (int u = 0; u < 4; ++u) {
                const int r = rr[u];
                const int b = r / RPB;                       // const div -> magic mul
                const int pack = ((r - b * RPB) << 17) | cc[u];
                const int p = atomicAdd(&lcnt[b], 1);
                if (p < CAP) {
                    lbuf[b * CAP + p] = pack;
                } else {  // statistically-never spill (kept for unconditional correctness)
                    const int gp = atomicAdd(&bcur[b], 1);
                    bp[b * BCAP + gp] = pack;
                }
            }
        }
    }
    __syncthreads();
    {
        const int tot = min(lcnt[tid], CAP);
        ltot[tid] = tot;
        lbase[tid] = atomicAdd(&bcur[tid], tot);
    }
    __syncthreads();
    // flush: 32-lane group per bucket -> coalesced packed stores
    #pragma unroll
    for (int k = 0; k < 32; ++k) {
        const int b = (k << 3) + (tid >> 5);
        const int i = tid & 31;
        if (i < ltot[b]) bp[b * BCAP + lbase[b] + i] = lbuf[b * CAP + i];
    }
}

// ---------------- CSR step 2: per-bucket LDS counting sort (zero global atomics) ----------------
// One block per bucket: stage bucket edges in LDS, LDS-histogram 391 rows, LDS scan ->
// writes offsets[] directly, then place into a contiguous sorted_cols window via LDS cursors.
__global__ __launch_bounds__(256) void sort_kernel(const int* __restrict__ bp,
                                                   const int* __restrict__ bcur,
                                                   int* __restrict__ offsets,
                                                   int* __restrict__ sorted_cols) {
    __shared__ int ebuf[BCAP];       // 27.6 KB staged bucket edges
    __shared__ int sa[256], sb2[256];
    __shared__ int hist[512];
    __shared__ int cur[RPB + 1];
    const int b = blockIdx.x, t = threadIdx.x;

    sa[t] = bcur[t];
    hist[t] = 0; hist[t + 256] = 0;
    __syncthreads();

    // inclusive scan of bucket sizes -> global base of this bucket
    int* src = sa; int* dst = sb2;
    for (int off = 1; off < 256; off <<= 1) {
        const int v = src[t] + ((t >= off) ? src[t - off] : 0);
        dst[t] = v; __syncthreads();
        int* tmp = src; src = dst; dst = tmp;
    }
    const int n = bcur[b];
    const int gbase = src[b] - n;    // exclusive base
    const int bb = b * BCAP;

    // Pass A: stage to LDS + histogram (no-return LDS atomics)
    int i = t;
    for (; i + 768 < n; i += 1024) {
        const int v0 = bp[bb + i], v1 = bp[bb + i + 256];
        const int v2 = bp[bb + i + 512], v3 = bp[bb + i + 768];
        ebuf[i] = v0; ebuf[i + 256] = v1; ebuf[i + 512] = v2; ebuf[i + 768] = v3;
        atomicAdd(&hist[v0 >> 17], 1);
        atomicAdd(&hist[v1 >> 17], 1);
        atomicAdd(&hist[v2 >> 17], 1);
        atomicAdd(&hist[v3 >> 17], 1);
    }
    for (; i < n; i += 256) {
        const int v = bp[bb + i];
        ebuf[i] = v;
        atomicAdd(&hist[v >> 17], 1);
    }
    __syncthreads();

    // scan hist[512] (thread t owns elements 2t, 2t+1) -> exclusive per-row offsets
    const int h0 = hist[2 * t], h1 = hist[2 * t + 1];
    const int sum2 = h0 + h1;
    sa[t] = sum2; __syncthreads();
    src = sa; dst = sb2;
    for (int off = 1; off < 256; off <<= 1) {
        const int v = src[t] + ((t >= off) ? src[t - off] : 0);
        dst[t] = v; __syncthreads();
        int* tmp = src; src = dst; dst = tmp;
    }
    const int S = src[t];
    const int e0 = 2 * t, e1 = 2 * t + 1;
    const int x0 = S - sum2;   // exclusive at e0
    const int x1 = S - h1;     // exclusive at e1
    if (e0 < RPB) {
        cur[e0] = x0;
        const int row = b * RPB + e0;
        if (row <= N_NODES) offsets[row] = gbase + x0;
    }
    if (e1 < RPB) {
        cur[e1] = x1;
        const int row = b * RPB + e1;
        if (row <= N_NODES) offsets[row] = gbase + x1;
    }
    __syncthreads();

    // Pass B: place via LDS cursor atomics; stores land in a contiguous 25KB window
    i = t;
    for (; i + 768 < n; i += 1024) {
        const int v0 = ebuf[i], v1 = ebuf[i + 256], v2 = ebuf[i + 512], v3 = ebuf[i + 768];
        const int p0 = atomicAdd(&cur[v0 >> 17], 1);
        const int p1 = atomicAdd(&cur[v1 >> 17], 1);
        const int p2 = atomicAdd(&cur[v2 >> 17], 1);
        const int p3 = atomicAdd(&cur[v3 >> 17], 1);
        sorted_cols[gbase + p0] = v0 & 0x1FFFF;
        sorted_cols[gbase + p1] = v1 & 0x1FFFF;
        sorted_cols[gbase + p2] = v2 & 0x1FFFF;
        sorted_cols[gbase + p3] = v3 & 0x1FFFF;
    }
    for (; i < n; i += 256) {
        const int v = ebuf[i];
        const int p = atomicAdd(&cur[v >> 17], 1);
        sorted_cols[gbase + p] = v & 0x1FFFF;
    }
}

// ---------------- Pull-mode aggregate (fp16 gather) + fused sigmoid ----------------
__global__ __launch_bounds__(256) void aggregate_kernel(const int* __restrict__ offsets,
                                                        const int* __restrict__ sorted_cols,
                                                        const __half* __restrict__ x,
                                                        float* __restrict__ out) {
    const int row = blockIdx.x * 4 + (threadIdx.x >> 6);
    const int lane = threadIdx.x & 63;
    if (row >= N_NODES) return;
    const int start = offsets[row];
    const int end = offsets[row + 1];
    float acc = 0.f;
    int j = start;
    for (; j + 7 < end; j += 8) {
        int c[8];
        #pragma unroll
        for (int u = 0; u < 8; ++u) c[u] = sorted_cols[j + u];
        float a[8];
        #pragma unroll
        for (int u = 0; u < 8; ++u) a[u] = __half2float(x[(size_t)c[u] * OUT_DIM + lane]);
        acc += ((a[0] + a[1]) + (a[2] + a[3])) + ((a[4] + a[5]) + (a[6] + a[7]));
    }
    for (; j < end; ++j)
        acc += __half2float(x[(size_t)sorted_cols[j] * OUT_DIM + lane]);
    out[(size_t)row * OUT_DIM + lane] = 1.f / (1.f + __expf(-acc));
}

extern "C" void kernel_launch(void* const* d_in, const int* in_sizes, int n_in,
                              void* d_out, int out_size, void* d_ws, size_t ws_size,
                              hipStream_t stream) {
    const float* inputs = (const float*)d_in[0];
    const int* edge_index = (const int*)d_in[1];  // [2, N_EDGES], int32 on device
    const float* weight = (const float*)d_in[2];
    float* out = (float*)d_out;

    char* ws = (char*)d_ws;
    __half* x        = (__half*)(ws + X_OFF);
    int* bp          = (int*)(ws + X_OFF);        // time-aliases x: dead before gemm writes
    ushort* wimg     = (ushort*)(ws + WIMG_OFF);
    int* offsets     = (int*)(ws + OFFSETS_OFF);
    int* bcur        = (int*)(ws + BCUR_OFF);
    int* sorted_cols = (int*)(ws + SORTED_OFF);

    const int* rows = edge_index;
    const int* cols = edge_index + N_EDGES;

    hipMemsetAsync(bcur, 0, NB * sizeof(int), stream);

    // ---- CSR build (two-level LDS counting sort; ~200K global atomics total) ----
    bin_kernel<<<NBIN_BLK, 256, 0, stream>>>(rows, cols, bcur, bp);
    sort_kernel<<<NB, 256, 0, stream>>>(bp, bcur, offsets, sorted_cols);

    // ---- dense projection (x overwrites bp region after sort consumed it) ----
    convert_weight<<<64, 256, 0, stream>>>(weight, wimg);
    gemm_mfma<<<(N_NODES + 63) / 64, 256, 0, stream>>>(inputs, wimg, x);

    // ---- gather-aggregate + sigmoid ----
    aggregate_kernel<<<(N_NODES + 3) / 4, 256, 0, stream>>>(offsets, sorted_cols, x, out);
}

// Round 3
// 261.242 us; speedup vs baseline: 1.4822x; 1.0526x over previous
//
#include <hip/hip_runtime.h>
#include <hip/hip_fp16.h>
#include <math.h>

#define N_NODES 100000
#define N_EDGES 1600000
#define IN_DIM 256
#define OUT_DIM 64

// ---- two-level LDS counting sort ----
#define NB 256                   // buckets
#define RPB 391                  // rows per bucket; 256*391 = 100096 >= N_NODES
#define BCAP 6912                // per-bucket global capacity (mean 6250, +8.3 sd)
#define CAP 32                   // per-bucket LDS staging slots (mean 8, Poisson tail ~1e-12/cell)
#define CHUNK_E 2048             // edges per bin block
#define NBIN_BLK ((N_EDGES + CHUNK_E - 1) / CHUNK_E)  // 782

// ---- workspace layout (bytes) ----
// [0, 25.6MB): time-shared — packed buckets bp[NB][BCAP] (7.08MB) during CSR build,
// then x[N_NODES][64] fp16 (12.8MB) written by gemm AFTER sort_kernel consumed bp.
#define X_OFF         0UL
#define WIMG_OFF      25600000UL   // 64KB weight image
#define OFFSETS_OFF   26000000UL   // 400,004 B: int offsets[N_NODES+1]
#define BCUR_OFF      26400016UL   // 1KB: int bcur[NB]
#define SORTED_OFF    26801088UL   // 6,400,000 B: int sorted_cols[N_EDGES]
// total ~33.2 MB (same footprint as proven layout)

typedef short bf16x8 __attribute__((ext_vector_type(8)));
typedef float f32x4 __attribute__((ext_vector_type(4)));

// ---------------- Weight -> bf16 hi/lo B-fragment image (64 KB) ----------------
__global__ __launch_bounds__(256) void convert_weight(const float* __restrict__ w,
                                                      ushort* __restrict__ img) {
    const int g = blockIdx.x * 256 + threadIdx.x;  // 0..16383
    const int j = g & 7, l = (g >> 3) & 63, ts = g >> 9;  // ts = t*8+s
    const int s = ts & 7, t = ts >> 3;
    const int k = s * 32 + (l >> 4) * 8 + j;
    const int c = t * 16 + (l & 15);
    const float v = w[k * OUT_DIM + c];
    const unsigned b = __float_as_uint(v);
    const float r = v - __uint_as_float(b & 0xFFFF0000u);  // residual after hi-truncation
    img[(ts * 2 + 0) * 512 + l * 8 + j] = (ushort)(b >> 16);
    img[(ts * 2 + 1) * 512 + l * 8 + j] = (ushort)(__float_as_uint(r) >> 16);
}

// ---------------- GEMM via MFMA, fp32 accuracy by bf16 hi/lo 3-term split ----------------
__global__ __launch_bounds__(256) void gemm_mfma(const float* __restrict__ inputs,
                                                 const ushort* __restrict__ wimg,
                                                 __half* __restrict__ x) {
    __shared__ ushort lds[32768];  // 64 KB -> 2 blocks/CU
    const int tid = threadIdx.x;

    #pragma unroll
    for (int i = 0; i < 16; ++i) {
        const int c = tid + i * 256;  // 16B-chunk index 0..4095
        *(int4*)(lds + c * 8) = *(const int4*)(wimg + c * 8);
    }
    __syncthreads();

    const int wv = tid >> 6, l = tid & 63;
    const int rbase = blockIdx.x * 64 + wv * 16;
    const int arow_idx = rbase + (l & 15);
    const int row_c = arow_idx < N_NODES ? arow_idx : N_NODES - 1;  // clamp loads; stores guarded
    const float* arow = inputs + (size_t)row_c * IN_DIM;
    const int koff = (l >> 4) * 8;

    bf16x8 ah[8], al[8];
    #pragma unroll
    for (int s = 0; s < 8; ++s) {
        const float4 p = *(const float4*)(arow + s * 32 + koff);
        const float4 q = *(const float4*)(arow + s * 32 + koff + 4);
        const float v[8] = {p.x, p.y, p.z, p.w, q.x, q.y, q.z, q.w};
        #pragma unroll
        for (int j = 0; j < 8; ++j) {
            const unsigned b = __float_as_uint(v[j]);
            const float r = v[j] - __uint_as_float(b & 0xFFFF0000u);
            ah[s][j] = (short)(b >> 16);
            al[s][j] = (short)(__float_as_uint(r) >> 16);
        }
    }

    f32x4 acc[4];
    #pragma unroll
    for (int t = 0; t < 4; ++t) acc[t] = (f32x4){0.f, 0.f, 0.f, 0.f};

    const bf16x8* b8 = (const bf16x8*)lds;
    #pragma unroll
    for (int t = 0; t < 4; ++t) {
        #pragma unroll
        for (int s = 0; s < 8; ++s) {
            const bf16x8 bh = b8[((t * 8 + s) * 2 + 0) * 64 + l];
            const bf16x8 blo = b8[((t * 8 + s) * 2 + 1) * 64 + l];
            acc[t] = __builtin_amdgcn_mfma_f32_16x16x32_bf16(ah[s], bh, acc[t], 0, 0, 0);
            acc[t] = __builtin_amdgcn_mfma_f32_16x16x32_bf16(al[s], bh, acc[t], 0, 0, 0);
            acc[t] = __builtin_amdgcn_mfma_f32_16x16x32_bf16(ah[s], blo, acc[t], 0, 0, 0);
        }
    }

    const int mbase = rbase + (l >> 4) * 4;
    #pragma unroll
    for (int reg = 0; reg < 4; ++reg) {
        const int row = mbase + reg;
        if (row < N_NODES) {
            #pragma unroll
            for (int t = 0; t < 4; ++t)
                x[(size_t)row * OUT_DIM + t * 16 + (l & 15)] = __float2half(acc[t][reg]);
        }
    }
}

// ---------------- CSR step 1: bin edges into 256 row-buckets (packed 4B) ----------------
// pack = (rloc << 17) | col, rloc = r - bucket*RPB (<391 -> 9 bits), col < 2^17.
// Only global atomics: one reservation per (block,bucket) = 200K total.
__global__ __launch_bounds__(256) void bin_kernel(const int* __restrict__ rows,
                                                  const int* __restrict__ cols,
                                                  int* __restrict__ bcur,
                                                  int* __restrict__ bp) {
    __shared__ int lbuf[NB * CAP];   // 32 KB
    __shared__ int lcnt[NB], ltot[NB], lbase[NB];
    const int tid = threadIdx.x;
    lcnt[tid] = 0;
    __syncthreads();

    const int base = blockIdx.x * CHUNK_E;
    #pragma unroll
    for (int g = 0; g < 2; ++g) {
        const int e = base + (g * 256 + tid) * 4;
        if (e < N_EDGES) {  // N_EDGES % 4 == 0, whole int4 in range
            const int4 r4 = *(const int4*)(rows + e);
            const int4 c4 = *(const int4*)(cols + e);
            const int rr[4] = {r4.x, r4.y, r4.z, r4.w};
            const int cc[4] = {c4.x, c4.y, c4.z, c4.w};
            #pragma unroll
            for (int u = 0; u < 4; ++u) {
                const int r = rr[u];
                const int b = r / RPB;                       // const div -> magic mul
                const int pack = ((r - b * RPB) << 17) | cc[u];
                const int p = atomicAdd(&lcnt[b], 1);
                if (p < CAP) {
                    lbuf[b * CAP + p] = pack;
                } else {  // statistically-never spill (kept for unconditional correctness)
                    const int gp = atomicAdd(&bcur[b], 1);
                    bp[b * BCAP + gp] = pack;
                }
            }
        }
    }
    __syncthreads();
    {
        const int tot = min(lcnt[tid], CAP);
        ltot[tid] = tot;
        lbase[tid] = atomicAdd(&bcur[tid], tot);
    }
    __syncthreads();
    // flush: 32-lane group per bucket -> coalesced packed stores
    #pragma unroll
    for (int k = 0; k < 32; ++k) {
        const int b = (k << 3) + (tid >> 5);
        const int i = tid & 31;
        if (i < ltot[b]) bp[b * BCAP + lbase[b] + i] = lbuf[b * CAP + i];
    }
}

// ---------------- CSR step 2: per-bucket LDS counting sort (zero global atomics) ----------------
__global__ __launch_bounds__(256) void sort_kernel(const int* __restrict__ bp,
                                                   const int* __restrict__ bcur,
                                                   int* __restrict__ offsets,
                                                   int* __restrict__ sorted_cols) {
    __shared__ int ebuf[BCAP];       // 27.6 KB staged bucket edges
    __shared__ int sa[256], sb2[256];
    __shared__ int hist[512];
    __shared__ int cur[RPB + 1];
    const int b = blockIdx.x, t = threadIdx.x;

    sa[t] = bcur[t];
    hist[t] = 0; hist[t + 256] = 0;
    __syncthreads();

    // inclusive scan of bucket sizes -> global base of this bucket
    int* src = sa; int* dst = sb2;
    for (int off = 1; off < 256; off <<= 1) {
        const int v = src[t] + ((t >= off) ? src[t - off] : 0);
        dst[t] = v; __syncthreads();
        int* tmp = src; src = dst; dst = tmp;
    }
    const int n = bcur[b];
    const int gbase = src[b] - n;    // exclusive base
    const int bb = b * BCAP;

    // Pass A: stage to LDS + histogram (no-return LDS atomics)
    int i = t;
    for (; i + 768 < n; i += 1024) {
        const int v0 = bp[bb + i], v1 = bp[bb + i + 256];
        const int v2 = bp[bb + i + 512], v3 = bp[bb + i + 768];
        ebuf[i] = v0; ebuf[i + 256] = v1; ebuf[i + 512] = v2; ebuf[i + 768] = v3;
        atomicAdd(&hist[v0 >> 17], 1);
        atomicAdd(&hist[v1 >> 17], 1);
        atomicAdd(&hist[v2 >> 17], 1);
        atomicAdd(&hist[v3 >> 17], 1);
    }
    for (; i < n; i += 256) {
        const int v = bp[bb + i];
        ebuf[i] = v;
        atomicAdd(&hist[v >> 17], 1);
    }
    __syncthreads();

    // scan hist[512] (thread t owns elements 2t, 2t+1) -> exclusive per-row offsets
    const int h0 = hist[2 * t], h1 = hist[2 * t + 1];
    const int sum2 = h0 + h1;
    sa[t] = sum2; __syncthreads();
    src = sa; dst = sb2;
    for (int off = 1; off < 256; off <<= 1) {
        const int v = src[t] + ((t >= off) ? src[t - off] : 0);
        dst[t] = v; __syncthreads();
        int* tmp = src; src = dst; dst = tmp;
    }
    const int S = src[t];
    const int e0 = 2 * t, e1 = 2 * t + 1;
    const int x0 = S - sum2;   // exclusive at e0
    const int x1 = S - h1;     // exclusive at e1
    if (e0 < RPB) {
        cur[e0] = x0;
        const int row = b * RPB + e0;
        if (row <= N_NODES) offsets[row] = gbase + x0;
    }
    if (e1 < RPB) {
        cur[e1] = x1;
        const int row = b * RPB + e1;
        if (row <= N_NODES) offsets[row] = gbase + x1;
    }
    __syncthreads();

    // Pass B: place via LDS cursor atomics; stores land in a contiguous 25KB window
    i = t;
    for (; i + 768 < n; i += 1024) {
        const int v0 = ebuf[i], v1 = ebuf[i + 256], v2 = ebuf[i + 512], v3 = ebuf[i + 768];
        const int p0 = atomicAdd(&cur[v0 >> 17], 1);
        const int p1 = atomicAdd(&cur[v1 >> 17], 1);
        const int p2 = atomicAdd(&cur[v2 >> 17], 1);
        const int p3 = atomicAdd(&cur[v3 >> 17], 1);
        sorted_cols[gbase + p0] = v0 & 0x1FFFF;
        sorted_cols[gbase + p1] = v1 & 0x1FFFF;
        sorted_cols[gbase + p2] = v2 & 0x1FFFF;
        sorted_cols[gbase + p3] = v3 & 0x1FFFF;
    }
    for (; i < n; i += 256) {
        const int v = ebuf[i];
        const int p = atomicAdd(&cur[v >> 17], 1);
        sorted_cols[gbase + p] = v & 0x1FFFF;
    }
}

// ---------------- Pull-mode aggregate (fp16 gather) + fused sigmoid ----------------
// Wave = 4 edge-groups x 16 lanes; each 16-lane group reads a full 128B x-row
// (8B/lane = 4 cols) -> 4 edges gathered per instruction. Average row (16 edges)
// completes in 1 main iteration + 1 guarded tail pass (~2 memory round trips).
__global__ __launch_bounds__(256) void aggregate_kernel(const int* __restrict__ offsets,
                                                        const int* __restrict__ sorted_cols,
                                                        const __half* __restrict__ x,
                                                        float* __restrict__ out) {
    const int row = blockIdx.x * 4 + (threadIdx.x >> 6);
    const int lane = threadIdx.x & 63;
    const int g = lane >> 4;       // edge slot 0..3
    const int s = lane & 15;       // column slice: cols 4s..4s+3
    if (row >= N_NODES) return;
    const int start = offsets[row];
    const int end = offsets[row + 1];
    const __half* xs = x + s * 4;

    float a0 = 0.f, a1 = 0.f, a2 = 0.f, a3 = 0.f;
    int j = start;
    // main: 16 edges per pass (4 per group), cols batched then gathers batched
    for (; j + 15 < end; j += 16) {
        int c[4];
        #pragma unroll
        for (int u = 0; u < 4; ++u) c[u] = sorted_cols[j + u * 4 + g];
        #pragma unroll
        for (int u = 0; u < 4; ++u) {
            const uint2 d = *(const uint2*)(xs + (size_t)c[u] * OUT_DIM);
            const float2 f0 = __half22float2(*(const __half2*)&d.x);
            const float2 f1 = __half22float2(*(const __half2*)&d.y);
            a0 += f0.x; a1 += f0.y; a2 += f1.x; a3 += f1.y;
        }
    }
    // tail: up to 15 edges in ONE guarded pass (4 slots per group)
    #pragma unroll
    for (int u = 0; u < 4; ++u) {
        const int ej = j + u * 4 + g;
        if (ej < end) {
            const int cc = sorted_cols[ej];
            const uint2 d = *(const uint2*)(xs + (size_t)cc * OUT_DIM);
            const float2 f0 = __half22float2(*(const __half2*)&d.x);
            const float2 f1 = __half22float2(*(const __half2*)&d.y);
            a0 += f0.x; a1 += f0.y; a2 += f1.x; a3 += f1.y;
        }
    }
    // combine the 4 edge-groups (lane bits 4,5)
    a0 += __shfl_xor(a0, 16); a0 += __shfl_xor(a0, 32);
    a1 += __shfl_xor(a1, 16); a1 += __shfl_xor(a1, 32);
    a2 += __shfl_xor(a2, 16); a2 += __shfl_xor(a2, 32);
    a3 += __shfl_xor(a3, 16); a3 += __shfl_xor(a3, 32);

    if (lane < 16) {
        float4 o;
        o.x = 1.f / (1.f + __expf(-a0));
        o.y = 1.f / (1.f + __expf(-a1));
        o.z = 1.f / (1.f + __expf(-a2));
        o.w = 1.f / (1.f + __expf(-a3));
        *(float4*)(out + (size_t)row * OUT_DIM + s * 4) = o;
    }
}

extern "C" void kernel_launch(void* const* d_in, const int* in_sizes, int n_in,
                              void* d_out, int out_size, void* d_ws, size_t ws_size,
                              hipStream_t stream) {
    const float* inputs = (const float*)d_in[0];
    const int* edge_index = (const int*)d_in[1];  // [2, N_EDGES], int32 on device
    const float* weight = (const float*)d_in[2];
    float* out = (float*)d_out;

    char* ws = (char*)d_ws;
    __half* x        = (__half*)(ws + X_OFF);
    int* bp          = (int*)(ws + X_OFF);        // time-aliases x: dead before gemm writes
    ushort* wimg     = (ushort*)(ws + WIMG_OFF);
    int* offsets     = (int*)(ws + OFFSETS_OFF);
    int* bcur        = (int*)(ws + BCUR_OFF);
    int* sorted_cols = (int*)(ws + SORTED_OFF);

    const int* rows = edge_index;
    const int* cols = edge_index + N_EDGES;

    hipMemsetAsync(bcur, 0, NB * sizeof(int), stream);

    // ---- CSR build (two-level LDS counting sort; ~200K global atomics total) ----
    bin_kernel<<<NBIN_BLK, 256, 0, stream>>>(rows, cols, bcur, bp);
    sort_kernel<<<NB, 256, 0, stream>>>(bp, bcur, offsets, sorted_cols);

    // ---- dense projection (x overwrites bp region after sort consumed it) ----
    convert_weight<<<64, 256, 0, stream>>>(weight, wimg);
    gemm_mfma<<<(N_NODES + 63) / 64, 256, 0, stream>>>(inputs, wimg, x);

    // ---- gather-aggregate + sigmoid ----
    aggregate_kernel<<<(N_NODES + 3) / 4, 256, 0, stream>>>(offsets, sorted_cols, x, out);
}